// Round 4
// baseline (627.865 us; speedup 1.0000x reference)
//
#include <hip/hip_runtime.h>

typedef __attribute__((ext_vector_type(8))) short short8;
typedef __attribute__((ext_vector_type(4))) float f32x4;

__device__ __forceinline__ float bf2f(unsigned short u){
  return __uint_as_float(((unsigned int)u) << 16);
}
__device__ __forceinline__ unsigned short f2bf(float f){
  unsigned int u = __float_as_uint(f);
  u += 0x7fffu + ((u >> 16) & 1u);   // RNE
  return (unsigned short)(u >> 16);
}
// dtype-dispatching scalar load: isF32 ? f32[i] : bf16[i]
__device__ __forceinline__ float ldf(const void* p, long i, int isF32){
  return isF32 ? ((const float*)p)[i] : bf2f(((const unsigned short*)p)[i]);
}

// ---- prep: dtype detect (block 0) + row_ptr from sorted rows ----
__global__ void prep_k(const int* __restrict__ rows, int* __restrict__ rs,
                       int E, int N, const unsigned short* __restrict__ x,
                       int* __restrict__ flag){
  if (blockIdx.x == 0){
    __shared__ int s;
    if (threadIdx.x == 0) s = 0;
    __syncthreads();
    int bad = 0;
    for (int i = threadIdx.x; i < 2048; i += 256){
      unsigned int e = ((unsigned int)x[2 * i] >> 7) & 0xffu;
      if (e >= 0xF0u) bad = 1;
    }
    if (bad) atomicOr(&s, 1);
    __syncthreads();
    if (threadIdx.x == 0) *flag = s;
  }
  int e = blockIdx.x * 256 + threadIdx.x;
  if (e >= E) return;
  if (e == 0){
    for (int r = 0; r <= rows[0]; ++r) rs[r] = 0;
  } else {
    int a = rows[e - 1], b = rows[e];
    for (int r = a + 1; r <= b; ++r) rs[r] = e;
  }
  if (e == E - 1){
    for (int r = rows[E - 1] + 1; r <= N; ++r) rs[r] = E;
  }
}

// ---- fused transpose of all three W matrices -> canonical bf16 WT ----
__global__ void wtrans_all(const void* __restrict__ Wres,
                           const void* __restrict__ W1,
                           const void* __restrict__ W2,
                           unsigned short* __restrict__ WresT,
                           unsigned short* __restrict__ W1T,
                           unsigned short* __restrict__ W2T,
                           const int* __restrict__ flag){
  int isF32 = *flag;
  int b = blockIdx.x;
  const void* W; unsigned short* WT; int K; int idx;
  if (b < 128)      { W = Wres; WT = WresT; K = 256; idx = b * 256 + threadIdx.x; }
  else if (b < 256) { W = W1;   WT = W1T;   K = 256; idx = (b - 128) * 256 + threadIdx.x; }
  else              { W = W2;   WT = W2T;   K = 128; idx = (b - 256) * 256 + threadIdx.x; }
  if (idx >= K * 128) return;
  int n = idx / K, k = idx - n * K;
  WT[idx] = f2bf(ldf(W, (long)k * 128 + n, isF32));
}

// ============================================================
// Fused dual GEMM (R2-measured structure, epilogue -> slice-major):
// z = x@Wres + bres, y1 = x@W1, one A-read.
// Output layout: [8 slices][N][16] bf16 (slice = col>>4 = nt).
// ============================================================
__global__ __launch_bounds__(256, 2) void gemm_zy1(
    const void* __restrict__ A,
    const unsigned short* __restrict__ WT0,  // WresT [128][256]
    const unsigned short* __restrict__ WT1,  // W1T   [128][256]
    const void* __restrict__ bias0,
    unsigned short* __restrict__ out0,       // z  slice-major
    unsigned short* __restrict__ out1,       // y1 slice-major
    int M, const int* __restrict__ flagp)
{
  constexpr int K = 256, KB = 128;
  __shared__ __align__(16) unsigned short lW[2 * 128 * 128];  // 64 KB

  const int fl   = *flagp;
  const int tid  = threadIdx.x;
  const int lane = tid & 63;
  const int wav  = tid >> 6;
  const int l16  = lane & 15;
  const int quad = lane >> 4;
  const int rowBase = blockIdx.x * 128 + wav * 32;

  f32x4 acc[2][2][8];   // [w][s][nt]
#pragma unroll
  for (int w = 0; w < 2; ++w)
#pragma unroll
    for (int s = 0; s < 2; ++s)
#pragma unroll
      for (int nt = 0; nt < 8; ++nt) acc[w][s][nt] = (f32x4){0.f, 0.f, 0.f, 0.f};

  for (int kb = 0; kb < K; kb += KB){
    __syncthreads();
#pragma unroll
    for (int i = tid; i < 2 * 128 * 16; i += 256){
      int t = i >> 11;
      int j = i & 2047;
      int n = j >> 4;
      int c = j & 15;
      const unsigned short* WT = t ? WT1 : WT0;
      *(short8*)&lW[(t * 128 + n) * 128 + ((c * 8) ^ ((n & 7) * 8))] =
          *(const short8*)&WT[n * K + kb + c * 8];
    }
    short8 af[2][4];
    if (fl){
#pragma unroll
      for (int s = 0; s < 2; ++s){
        int r = rowBase + s * 16 + l16;
        const float* Af = (const float*)A + (long)r * K + kb + quad * 8;
        f32x4 t0[4], t1[4];
#pragma unroll
        for (int q = 0; q < 4; ++q){
          if (r < M){
            t0[q] = *(const f32x4*)(Af + q * 32);
            t1[q] = *(const f32x4*)(Af + q * 32 + 4);
          } else {
            t0[q] = (f32x4){0.f, 0.f, 0.f, 0.f};
            t1[q] = (f32x4){0.f, 0.f, 0.f, 0.f};
          }
        }
#pragma unroll
        for (int q = 0; q < 4; ++q){
          short8 v;
          v[0] = (short)f2bf(t0[q][0]); v[1] = (short)f2bf(t0[q][1]);
          v[2] = (short)f2bf(t0[q][2]); v[3] = (short)f2bf(t0[q][3]);
          v[4] = (short)f2bf(t1[q][0]); v[5] = (short)f2bf(t1[q][1]);
          v[6] = (short)f2bf(t1[q][2]); v[7] = (short)f2bf(t1[q][3]);
          af[s][q] = v;
        }
      }
    } else {
#pragma unroll
      for (int s = 0; s < 2; ++s){
        int r = rowBase + s * 16 + l16;
        const unsigned short* Ab = (const unsigned short*)A + (long)r * K + kb + quad * 8;
#pragma unroll
        for (int q = 0; q < 4; ++q){
          short8 v = {};
          if (r < M) v = *(const short8*)(Ab + q * 32);
          af[s][q] = v;
        }
      }
    }
    __syncthreads();
#pragma unroll
    for (int q = 0; q < 4; ++q){
#pragma unroll
      for (int nt = 0; nt < 8; ++nt){
        int row = nt * 16 + l16;
        int bo  = row * 128 + ((q * 32 + quad * 8) ^ ((row & 7) * 8));
        short8 b0 = *(const short8*)&lW[bo];
        short8 b1 = *(const short8*)&lW[128 * 128 + bo];
        acc[0][0][nt] = __builtin_amdgcn_mfma_f32_16x16x32_bf16(af[0][q], b0, acc[0][0][nt], 0, 0, 0);
        acc[0][1][nt] = __builtin_amdgcn_mfma_f32_16x16x32_bf16(af[1][q], b0, acc[0][1][nt], 0, 0, 0);
        acc[1][0][nt] = __builtin_amdgcn_mfma_f32_16x16x32_bf16(af[0][q], b1, acc[1][0][nt], 0, 0, 0);
        acc[1][1][nt] = __builtin_amdgcn_mfma_f32_16x16x32_bf16(af[1][q], b1, acc[1][1][nt], 0, 0, 0);
      }
    }
  }

#pragma unroll
  for (int w = 0; w < 2; ++w){
    unsigned short* out = w ? out1 : out0;
#pragma unroll
    for (int s = 0; s < 2; ++s){
      int r0 = rowBase + s * 16 + quad * 4;
#pragma unroll
      for (int nt = 0; nt < 8; ++nt){
        float bv = (w == 0) ? ldf(bias0, nt * 16 + l16, fl) : 0.0f;
#pragma unroll
        for (int rg = 0; rg < 4; ++rg){
          int r = r0 + rg;
          if (r < M)
            out[(long)nt * M * 16 + (long)r * 16 + l16] = f2bf(acc[w][s][nt][rg] + bv);
        }
      }
    }
  }
}

// ============================================================
// XCD-sliced gather: slice = blockIdx.x & 7 (block->XCD round
// robin) so each XCD gathers only its 3.2 MB slice -> L2-hit.
// 8 lanes/edge, 8 edges per gather instruction, pairwise chunks.
// ============================================================
template<int FL>
__device__ __forceinline__ void slice_gather(
    int e0, int e1, const int* __restrict__ cols, const void* __restrict__ vals,
    const unsigned short* __restrict__ Ys, int g, int fi,
    float& a0, float& a1)
{
  a0 = 0.f; a1 = 0.f;
  if (e1 <= e0){
    return;
  }
  const int last = e1 - 1;
  for (int e = e0; e < e1; e += 16){
    int i1 = e + g, i2 = e + 8 + g;
    int k1 = i1 < last ? i1 : last;
    int k2 = i2 < last ? i2 : last;
    int c1 = cols[k1], c2 = cols[k2];
    float v1 = FL ? ((const float*)vals)[k1] : bf2f(((const unsigned short*)vals)[k1]);
    float v2 = FL ? ((const float*)vals)[k2] : bf2f(((const unsigned short*)vals)[k2]);
    v1 = (i1 < e1) ? v1 : 0.f;
    v2 = (i2 < e1) ? v2 : 0.f;
    unsigned int q1 = ((const unsigned int*)(Ys + (size_t)c1 * 16))[fi];
    unsigned int q2 = ((const unsigned int*)(Ys + (size_t)c2 * 16))[fi];
    a0 = fmaf(v1, bf2f((unsigned short)(q1 & 0xffffu)), a0);
    a1 = fmaf(v1, bf2f((unsigned short)(q1 >> 16)),     a1);
    a0 = fmaf(v2, bf2f((unsigned short)(q2 & 0xffffu)), a0);
    a1 = fmaf(v2, bf2f((unsigned short)(q2 >> 16)),     a1);
  }
#pragma unroll
  for (int off = 8; off <= 32; off <<= 1){
    a0 += __shfl_xor(a0, off);
    a1 += __shfl_xor(a1, off);
  }
}

// ---- spmm1: x1 = relu(agg(y1) + b1) + z, all slice-major bf16 ----
__global__ __launch_bounds__(256) void spmm1_s(
    const int* __restrict__ rs, const int* __restrict__ cols,
    const void* __restrict__ vals,
    const unsigned short* __restrict__ Y,   // y1 slice-major
    const unsigned short* __restrict__ z,   // slice-major
    const void* __restrict__ b1,
    unsigned short* __restrict__ x1,        // slice-major
    int N, const int* __restrict__ flagp)
{
  const int fl    = *flagp;
  const int lane  = threadIdx.x & 63;
  const int wav   = threadIdx.x >> 6;
  const int slice = blockIdx.x & 7;
  const int g  = lane >> 3;
  const int fi = lane & 7;
  const unsigned short* Ys = Y  + (size_t)slice * N * 16;
  const unsigned short* zs = z  + (size_t)slice * N * 16;
  unsigned short*       xs = x1 + (size_t)slice * N * 16;
  const float b0v = ldf(b1, slice * 16 + 2 * fi,     fl);
  const float b1v = ldf(b1, slice * 16 + 2 * fi + 1, fl);
  const int rowBase = ((blockIdx.x >> 3) * 4 + wav) * 16;
  for (int rr = 0; rr < 16; ++rr){
    int r = rowBase + rr;
    if (r >= N) return;
    int e0 = __builtin_amdgcn_readfirstlane(rs[r]);
    int e1 = __builtin_amdgcn_readfirstlane(rs[r + 1]);
    float a0, a1;
    if (fl) slice_gather<1>(e0, e1, cols, vals, Ys, g, fi, a0, a1);
    else    slice_gather<0>(e0, e1, cols, vals, Ys, g, fi, a0, a1);
    if (lane < 8){
      unsigned int zz = ((const unsigned int*)(zs + (size_t)r * 16))[fi];
      float r0 = fmaxf(a0 + b0v, 0.f) + bf2f((unsigned short)(zz & 0xffffu));
      float r1 = fmaxf(a1 + b1v, 0.f) + bf2f((unsigned short)(zz >> 16));
      ((unsigned int*)(xs + (size_t)r * 16))[fi] =
          (unsigned int)f2bf(r0) | ((unsigned int)f2bf(r1) << 16);
    }
  }
}

// ---- spmm2: agg2 = agg(x1), slice-major bf16 (bias/softmax later) ----
__global__ __launch_bounds__(256) void spmm2_s(
    const int* __restrict__ rs, const int* __restrict__ cols,
    const void* __restrict__ vals,
    const unsigned short* __restrict__ Y,   // x1 slice-major
    unsigned short* __restrict__ agg,       // slice-major out
    int N, const int* __restrict__ flagp)
{
  const int fl    = *flagp;
  const int lane  = threadIdx.x & 63;
  const int wav   = threadIdx.x >> 6;
  const int slice = blockIdx.x & 7;
  const int g  = lane >> 3;
  const int fi = lane & 7;
  const unsigned short* Ys = Y   + (size_t)slice * N * 16;
  unsigned short*       as = agg + (size_t)slice * N * 16;
  const int rowBase = ((blockIdx.x >> 3) * 4 + wav) * 16;
  for (int rr = 0; rr < 16; ++rr){
    int r = rowBase + rr;
    if (r >= N) return;
    int e0 = __builtin_amdgcn_readfirstlane(rs[r]);
    int e1 = __builtin_amdgcn_readfirstlane(rs[r + 1]);
    float a0, a1;
    if (fl) slice_gather<1>(e0, e1, cols, vals, Ys, g, fi, a0, a1);
    else    slice_gather<0>(e0, e1, cols, vals, Ys, g, fi, a0, a1);
    if (lane < 8){
      ((unsigned int*)(as + (size_t)r * 16))[fi] =
          (unsigned int)f2bf(a0) | ((unsigned int)f2bf(a1) << 16);
    }
  }
}

// ============================================================
// Final GEMM: out = log_softmax(agg2 @ W2 + b2).  Uses
// spmm/dense commutation: spmm(A, x1@W2) == spmm(A,x1)@W2.
// A = agg2 slice-major bf16; softmax fused in epilogue.
// ============================================================
__global__ __launch_bounds__(256, 3) void gemm_out(
    const unsigned short* __restrict__ A,    // agg2 slice-major [8][M][16]
    const unsigned short* __restrict__ WT,   // W2T [128][128]
    const void* __restrict__ b2,
    void* __restrict__ out, int M, const int* __restrict__ flagp)
{
  constexpr int K = 128;
  __shared__ __align__(16) unsigned short lW[128 * 128];   // 32 KB

  const int fl   = *flagp;
  const int tid  = threadIdx.x;
  const int lane = tid & 63;
  const int wav  = tid >> 6;
  const int l16  = lane & 15;
  const int quad = lane >> 4;
  const int rowBase = blockIdx.x * 128 + wav * 32;

#pragma unroll
  for (int i = tid; i < 128 * 16; i += 256){
    int n = i >> 4;
    int c = i & 15;
    *(short8*)&lW[n * 128 + ((c * 8) ^ ((n & 7) * 8))] = *(const short8*)&WT[n * K + c * 8];
  }
  // A loads: k-slice q*32+quad*8 .. +8 stays inside one 16-feat slice
  short8 af[2][4];
#pragma unroll
  for (int s = 0; s < 2; ++s){
    int r = rowBase + s * 16 + l16;
#pragma unroll
    for (int q = 0; q < 4; ++q){
      int k0 = q * 32 + quad * 8;
      short8 v = {};
      if (r < M)
        v = *(const short8*)&A[(size_t)(k0 >> 4) * M * 16 + (size_t)r * 16 + (k0 & 15)];
      af[s][q] = v;
    }
  }
  f32x4 acc[2][8];
#pragma unroll
  for (int s = 0; s < 2; ++s)
#pragma unroll
    for (int nt = 0; nt < 8; ++nt) acc[s][nt] = (f32x4){0.f, 0.f, 0.f, 0.f};
  __syncthreads();
#pragma unroll
  for (int q = 0; q < 4; ++q){
#pragma unroll
    for (int nt = 0; nt < 8; ++nt){
      int row = nt * 16 + l16;
      short8 b = *(const short8*)&lW[row * 128 + ((q * 32 + quad * 8) ^ ((row & 7) * 8))];
      acc[0][nt] = __builtin_amdgcn_mfma_f32_16x16x32_bf16(af[0][q], b, acc[0][nt], 0, 0, 0);
      acc[1][nt] = __builtin_amdgcn_mfma_f32_16x16x32_bf16(af[1][q], b, acc[1][nt], 0, 0, 0);
    }
  }
  // bias + fused log_softmax (row-wise over nt regs + l16 lanes)
  float bv[8];
#pragma unroll
  for (int nt = 0; nt < 8; ++nt) bv[nt] = ldf(b2, nt * 16 + l16, fl);
#pragma unroll
  for (int s = 0; s < 2; ++s){
#pragma unroll
    for (int rg = 0; rg < 4; ++rg){
      float v[8];
#pragma unroll
      for (int nt = 0; nt < 8; ++nt) v[nt] = acc[s][nt][rg] + bv[nt];
      float m = v[0];
#pragma unroll
      for (int nt = 1; nt < 8; ++nt) m = fmaxf(m, v[nt]);
#pragma unroll
      for (int off = 1; off <= 8; off <<= 1) m = fmaxf(m, __shfl_xor(m, off));
      float sum = 0.f;
#pragma unroll
      for (int nt = 0; nt < 8; ++nt) sum += expf(v[nt] - m);
#pragma unroll
      for (int off = 1; off <= 8; off <<= 1) sum += __shfl_xor(sum, off);
      float lse = m + logf(sum);
      int r = rowBase + s * 16 + quad * 4 + rg;
      if (r < M){
        if (fl){
          float* o = (float*)out + (long)r * 128 + l16;
#pragma unroll
          for (int nt = 0; nt < 8; ++nt) o[nt * 16] = v[nt] - lse;
        } else {
          unsigned short* o = (unsigned short*)out + (long)r * 128 + l16;
#pragma unroll
          for (int nt = 0; nt < 8; ++nt) o[nt * 16] = f2bf(v[nt] - lse);
        }
      }
    }
  }
}

extern "C" void kernel_launch(void* const* d_in, const int* in_sizes, int n_in,
                              void* d_out, int out_size, void* d_ws, size_t ws_size,
                              hipStream_t stream)
{
  const void* x    = d_in[0];
  const int*  erow = (const int*)d_in[1];
  const int*  ecol = (const int*)d_in[2];
  const void* eval = d_in[3];
  const void* Wres = d_in[4];
  const void* bres = d_in[5];
  const void* W1   = d_in[6];
  const void* b1   = d_in[7];
  const void* W2   = d_in[8];
  const void* b2   = d_in[9];
  const int N = in_sizes[0] / 256;   // 100000
  const int E = in_sizes[1];         // 1600000

  char* ws = (char*)d_ws;
  size_t szB = (size_t)N * 128 * 2;  // one bf16 [N,128] plane (25.6 MB)
  unsigned short* bufA  = (unsigned short*)ws;            // y1, then agg2
  unsigned short* bufC  = (unsigned short*)(ws + szB);    // x1
  unsigned short* WresT = (unsigned short*)(ws + 2 * szB);
  unsigned short* W1T   = WresT + 256 * 128;
  unsigned short* W2T   = W1T   + 256 * 128;
  int*            flag  = (int*)(W2T + 256 * 128);
  int*            rs    = flag + 4;                        // [N+1] row_ptr
  unsigned short* zbuf  = (unsigned short*)d_out;          // z (slice-major bf16)

  prep_k<<<(E + 255) / 256, 256, 0, stream>>>(erow, rs, E, N,
                                              (const unsigned short*)x, flag);
  wtrans_all<<<320, 256, 0, stream>>>(Wres, W1, W2, WresT, W1T, W2T, flag);

  const int gBlocks = (N + 127) / 128;
  const int sBlocksPerSlice = (N + 63) / 64;               // 4 waves x 16 rows
  const int sGrid = sBlocksPerSlice * 8;

  gemm_zy1<<<gBlocks, 256, 0, stream>>>(x, WresT, W1T, bres, zbuf, bufA, N, flag);

  spmm1_s<<<sGrid, 256, 0, stream>>>(rs, ecol, eval, bufA, zbuf, b1, bufC, N, flag);

  spmm2_s<<<sGrid, 256, 0, stream>>>(rs, ecol, eval, bufC, bufA, N, flag);

  gemm_out<<<gBlocks, 256, 0, stream>>>(bufA, W2T, b2, d_out, N, flag);
}

// Round 5
// 408.728 us; speedup vs baseline: 1.5361x; 1.5361x over previous
//
#include <hip/hip_runtime.h>

typedef __attribute__((ext_vector_type(8))) short short8;
typedef __attribute__((ext_vector_type(4))) float f32x4;

__device__ __forceinline__ float bf2f(unsigned short u){
  return __uint_as_float(((unsigned int)u) << 16);
}
__device__ __forceinline__ unsigned short f2bf(float f){
  unsigned int u = __float_as_uint(f);
  u += 0x7fffu + ((u >> 16) & 1u);   // RNE
  return (unsigned short)(u >> 16);
}
// dtype-dispatching scalar load: isF32 ? f32[i] : bf16[i]
__device__ __forceinline__ float ldf(const void* p, long i, int isF32){
  return isF32 ? ((const float*)p)[i] : bf2f(((const unsigned short*)p)[i]);
}

// ---- prep: dtype detect (block 0) + row_ptr from sorted rows ----
__global__ void prep_k(const int* __restrict__ rows, int* __restrict__ rs,
                       int E, int N, const unsigned short* __restrict__ x,
                       int* __restrict__ flag){
  if (blockIdx.x == 0){
    __shared__ int s;
    if (threadIdx.x == 0) s = 0;
    __syncthreads();
    int bad = 0;
    for (int i = threadIdx.x; i < 2048; i += 256){
      unsigned int e = ((unsigned int)x[2 * i] >> 7) & 0xffu;
      if (e >= 0xF0u) bad = 1;
    }
    if (bad) atomicOr(&s, 1);
    __syncthreads();
    if (threadIdx.x == 0) *flag = s;
  }
  int e = blockIdx.x * 256 + threadIdx.x;
  if (e >= E) return;
  if (e == 0){
    for (int r = 0; r <= rows[0]; ++r) rs[r] = 0;
  } else {
    int a = rows[e - 1], b = rows[e];
    for (int r = a + 1; r <= b; ++r) rs[r] = e;
  }
  if (e == E - 1){
    for (int r = rows[E - 1] + 1; r <= N; ++r) rs[r] = E;
  }
}

// ---- fused transpose of all three W matrices -> canonical bf16 WT ----
__global__ void wtrans_all(const void* __restrict__ Wres,
                           const void* __restrict__ W1,
                           const void* __restrict__ W2,
                           unsigned short* __restrict__ WresT,
                           unsigned short* __restrict__ W1T,
                           unsigned short* __restrict__ W2T,
                           const int* __restrict__ flag){
  int isF32 = *flag;
  int b = blockIdx.x;
  const void* W; unsigned short* WT; int K; int idx;
  if (b < 128)      { W = Wres; WT = WresT; K = 256; idx = b * 256 + threadIdx.x; }
  else if (b < 256) { W = W1;   WT = W1T;   K = 256; idx = (b - 128) * 256 + threadIdx.x; }
  else              { W = W2;   WT = W2T;   K = 128; idx = (b - 256) * 256 + threadIdx.x; }
  if (idx >= K * 128) return;
  int n = idx / K, k = idx - n * K;
  WT[idx] = f2bf(ldf(W, (long)k * 128 + n, isF32));
}

// ============================================================
// Fused dual GEMM v2: z = x@Wres + bres, y1 = x@W1, one A-read.
// BM=64 (wave: 16 rows x 128 cols x 2 planes -> acc 64 regs),
// KB=64 (two 128x64 W tiles = 32 KB LDS) -> 3 waves/SIMD.
// Row-major bf16 outputs.
// ============================================================
__global__ __launch_bounds__(256, 3) void gemm_zy1(
    const void* __restrict__ A,
    const unsigned short* __restrict__ WT0,  // WresT [128][256]
    const unsigned short* __restrict__ WT1,  // W1T   [128][256]
    const void* __restrict__ bias0,
    unsigned short* __restrict__ out0,       // z  [M][128] bf16
    unsigned short* __restrict__ out1,       // y1 [M][128] bf16
    int M, const int* __restrict__ flagp)
{
  constexpr int K = 256, KB = 64;
  __shared__ __align__(16) unsigned short lW[2 * 128 * KB];  // 32 KB

  const int fl   = *flagp;
  const int tid  = threadIdx.x;
  const int lane = tid & 63;
  const int wav  = tid >> 6;
  const int l16  = lane & 15;
  const int quad = lane >> 4;
  const int row  = blockIdx.x * 64 + wav * 16 + l16;   // A row for this lane
  const bool inM = row < M;

  f32x4 acc[2][8];   // [plane][nt]
#pragma unroll
  for (int w = 0; w < 2; ++w)
#pragma unroll
    for (int nt = 0; nt < 8; ++nt) acc[w][nt] = (f32x4){0.f, 0.f, 0.f, 0.f};

#pragma unroll
  for (int t = 0; t < K / KB; ++t){
    const int kb = t * KB;
    __syncthreads();   // previous-iter readers done
    // stage both W tiles: 2048 chunks of 8 shorts, XOR swizzle
#pragma unroll
    for (int j = 0; j < 8; ++j){
      int i  = tid + j * 256;
      int tl = i >> 10;
      int jj = i & 1023;
      int n  = jj >> 3, c = jj & 7;
      const unsigned short* WT = tl ? WT1 : WT0;
      *(short8*)&lW[(tl * 128 + n) * KB + ((c ^ (n & 7)) * 8)] =
          *(const short8*)&WT[n * K + kb + c * 8];
    }
    // A fragments for this K-tile (issued between barriers, overlap staging)
    short8 af[2];
    if (fl){
      f32x4 t0[2], t1[2];
#pragma unroll
      for (int q = 0; q < 2; ++q){
        t0[q] = (f32x4){0.f, 0.f, 0.f, 0.f};
        t1[q] = (f32x4){0.f, 0.f, 0.f, 0.f};
      }
      if (inM){
        const float* Af = (const float*)A + (long)row * K + kb + quad * 8;
#pragma unroll
        for (int q = 0; q < 2; ++q){
          t0[q] = *(const f32x4*)(Af + q * 32);
          t1[q] = *(const f32x4*)(Af + q * 32 + 4);
        }
      }
#pragma unroll
      for (int q = 0; q < 2; ++q){
        short8 v;
        v[0] = (short)f2bf(t0[q][0]); v[1] = (short)f2bf(t0[q][1]);
        v[2] = (short)f2bf(t0[q][2]); v[3] = (short)f2bf(t0[q][3]);
        v[4] = (short)f2bf(t1[q][0]); v[5] = (short)f2bf(t1[q][1]);
        v[6] = (short)f2bf(t1[q][2]); v[7] = (short)f2bf(t1[q][3]);
        af[q] = v;
      }
    } else {
#pragma unroll
      for (int q = 0; q < 2; ++q) af[q] = (short8){};
      if (inM){
        const unsigned short* Ab = (const unsigned short*)A + (long)row * K + kb + quad * 8;
#pragma unroll
        for (int q = 0; q < 2; ++q) af[q] = *(const short8*)(Ab + q * 32);
      }
    }
    __syncthreads();   // staging complete
#pragma unroll
    for (int q = 0; q < 2; ++q){
#pragma unroll
      for (int nt = 0; nt < 8; ++nt){
        int rw = nt * 16 + l16;
        int bo = rw * KB + (((q * 4 + quad) ^ (rw & 7)) * 8);
        short8 b0 = *(const short8*)&lW[bo];
        short8 b1 = *(const short8*)&lW[128 * KB + bo];
        acc[0][nt] = __builtin_amdgcn_mfma_f32_16x16x32_bf16(af[q], b0, acc[0][nt], 0, 0, 0);
        acc[1][nt] = __builtin_amdgcn_mfma_f32_16x16x32_bf16(af[q], b1, acc[1][nt], 0, 0, 0);
      }
    }
  }

  const int r0 = blockIdx.x * 64 + wav * 16 + quad * 4;
#pragma unroll
  for (int w = 0; w < 2; ++w){
    unsigned short* out = w ? out1 : out0;
#pragma unroll
    for (int nt = 0; nt < 8; ++nt){
      int col = nt * 16 + l16;
      float bv = (w == 0) ? ldf(bias0, col, fl) : 0.0f;
#pragma unroll
      for (int rg = 0; rg < 4; ++rg){
        int r = r0 + rg;
        if (r < M) out[(long)r * 128 + col] = f2bf(acc[w][nt][rg] + bv);
      }
    }
  }
}

// ============================================================
// y2 GEMM v2: out = A(bf16)@W2. BM=64, KB=64 (16 KB LDS),
// acc 32 regs -> 4 waves/SIMD.
// ============================================================
__global__ __launch_bounds__(256, 4) void gemm_y2(
    const unsigned short* __restrict__ A,    // x1 bf16 [M][128]
    const unsigned short* __restrict__ WT,   // W2T [128][128]
    unsigned short* __restrict__ out,
    int M)
{
  constexpr int K = 128, KB = 64;
  __shared__ __align__(16) unsigned short lW[128 * KB];   // 16 KB

  const int tid  = threadIdx.x;
  const int lane = tid & 63;
  const int wav  = tid >> 6;
  const int l16  = lane & 15;
  const int quad = lane >> 4;
  const int row  = blockIdx.x * 64 + wav * 16 + l16;
  const bool inM = row < M;

  f32x4 acc[8];
#pragma unroll
  for (int nt = 0; nt < 8; ++nt) acc[nt] = (f32x4){0.f, 0.f, 0.f, 0.f};

#pragma unroll
  for (int t = 0; t < K / KB; ++t){
    const int kb = t * KB;
    __syncthreads();
#pragma unroll
    for (int j = 0; j < 4; ++j){
      int i = tid + j * 256;
      int n = i >> 3, c = i & 7;
      *(short8*)&lW[n * KB + ((c ^ (n & 7)) * 8)] =
          *(const short8*)&WT[n * K + kb + c * 8];
    }
    short8 af[2];
#pragma unroll
    for (int q = 0; q < 2; ++q) af[q] = (short8){};
    if (inM){
      const unsigned short* Ab = A + (long)row * K + kb + quad * 8;
#pragma unroll
      for (int q = 0; q < 2; ++q) af[q] = *(const short8*)(Ab + q * 32);
    }
    __syncthreads();
#pragma unroll
    for (int q = 0; q < 2; ++q){
#pragma unroll
      for (int nt = 0; nt < 8; ++nt){
        int rw = nt * 16 + l16;
        short8 b = *(const short8*)&lW[rw * KB + (((q * 4 + quad) ^ (rw & 7)) * 8)];
        acc[nt] = __builtin_amdgcn_mfma_f32_16x16x32_bf16(af[q], b, acc[nt], 0, 0, 0);
      }
    }
  }

  const int r0 = blockIdx.x * 64 + wav * 16 + quad * 4;
#pragma unroll
  for (int nt = 0; nt < 8; ++nt){
    int col = nt * 16 + l16;
#pragma unroll
    for (int rg = 0; rg < 4; ++rg){
      int r = r0 + rg;
      if (r < M) out[(long)r * 128 + col] = f2bf(acc[nt][rg]);
    }
  }
}

// ---- R0-measured row-parallel gather: 2 feats/lane, MLP-4, scalar tail ----
__device__ __forceinline__ void row_gather(
    int e0, int e1, const int* __restrict__ cols, const void* __restrict__ vals,
    const unsigned short* __restrict__ Y, int lane, int fl,
    float& outx, float& outy)
{
  float ax0 = 0.f, ay0 = 0.f, ax1 = 0.f, ay1 = 0.f;
  int e = e0;
  for (; e + 4 <= e1; e += 4){
    int c0 = cols[e], c1 = cols[e + 1], c2 = cols[e + 2], c3 = cols[e + 3];
    float v0 = ldf(vals, e, fl),     v1 = ldf(vals, e + 1, fl);
    float v2 = ldf(vals, e + 2, fl), v3 = ldf(vals, e + 3, fl);
    unsigned int q0 = *(const unsigned int*)&Y[(long)c0 * 128 + 2 * lane];
    unsigned int q1 = *(const unsigned int*)&Y[(long)c1 * 128 + 2 * lane];
    unsigned int q2 = *(const unsigned int*)&Y[(long)c2 * 128 + 2 * lane];
    unsigned int q3 = *(const unsigned int*)&Y[(long)c3 * 128 + 2 * lane];
    ax0 = fmaf(v0, bf2f((unsigned short)(q0 & 0xffffu)), ax0);
    ay0 = fmaf(v0, bf2f((unsigned short)(q0 >> 16)),     ay0);
    ax1 = fmaf(v1, bf2f((unsigned short)(q1 & 0xffffu)), ax1);
    ay1 = fmaf(v1, bf2f((unsigned short)(q1 >> 16)),     ay1);
    ax0 = fmaf(v2, bf2f((unsigned short)(q2 & 0xffffu)), ax0);
    ay0 = fmaf(v2, bf2f((unsigned short)(q2 >> 16)),     ay0);
    ax1 = fmaf(v3, bf2f((unsigned short)(q3 & 0xffffu)), ax1);
    ay1 = fmaf(v3, bf2f((unsigned short)(q3 >> 16)),     ay1);
  }
  for (; e < e1; ++e){
    int c = cols[e];
    float v = ldf(vals, e, fl);
    unsigned int q = *(const unsigned int*)&Y[(long)c * 128 + 2 * lane];
    ax0 = fmaf(v, bf2f((unsigned short)(q & 0xffffu)), ax0);
    ay0 = fmaf(v, bf2f((unsigned short)(q >> 16)),     ay0);
  }
  outx = ax0 + ax1;
  outy = ay0 + ay1;
}

// ---- spmm1 fused: x1[r] = relu(spmm(y1)[r] + b1) + z[r], bf16 out ----
__global__ __launch_bounds__(256) void spmm1_f(
    const int* __restrict__ rs, const int* __restrict__ cols,
    const void* __restrict__ vals, const unsigned short* __restrict__ Y,
    const unsigned short* __restrict__ z, const void* __restrict__ b1,
    unsigned short* __restrict__ x1, int N, const int* __restrict__ flagp)
{
  const int fl   = *flagp;
  const int lane = threadIdx.x & 63;
  const int wav  = threadIdx.x >> 6;
  int r = blockIdx.x * 4 + wav;
  if (r >= N) return;
  int e0 = __builtin_amdgcn_readfirstlane(rs[r]);
  int e1 = __builtin_amdgcn_readfirstlane(rs[r + 1]);
  float ax, ay;
  row_gather(e0, e1, cols, vals, Y, lane, fl, ax, ay);
  long o = (long)r * 128 + 2 * lane;
  float b0 = ldf(b1, 2 * lane, fl), b1v = ldf(b1, 2 * lane + 1, fl);
  unsigned int zz = *(const unsigned int*)&z[o];
  float r0 = fmaxf(ax + b0,  0.f) + bf2f((unsigned short)(zz & 0xffffu));
  float r1 = fmaxf(ay + b1v, 0.f) + bf2f((unsigned short)(zz >> 16));
  *(unsigned int*)&x1[o] = (unsigned int)f2bf(r0) | ((unsigned int)f2bf(r1) << 16);
}

// ---- spmm2 fused: out[r] = log_softmax(spmm(y2)[r] + b2), dtype per flag ----
__global__ __launch_bounds__(256) void spmm2_f(
    const int* __restrict__ rs, const int* __restrict__ cols,
    const void* __restrict__ vals, const unsigned short* __restrict__ Y,
    const void* __restrict__ b2, void* __restrict__ out, int N,
    const int* __restrict__ flagp)
{
  const int fl   = *flagp;
  const int lane = threadIdx.x & 63;
  const int wav  = threadIdx.x >> 6;
  int r = blockIdx.x * 4 + wav;
  if (r >= N) return;
  int e0 = __builtin_amdgcn_readfirstlane(rs[r]);
  int e1 = __builtin_amdgcn_readfirstlane(rs[r + 1]);
  float ax, ay;
  row_gather(e0, e1, cols, vals, Y, lane, fl, ax, ay);
  float v0 = ax + ldf(b2, 2 * lane, fl);
  float v1 = ay + ldf(b2, 2 * lane + 1, fl);
  float m = fmaxf(v0, v1);
#pragma unroll
  for (int off = 32; off; off >>= 1) m = fmaxf(m, __shfl_xor(m, off));
  float s = expf(v0 - m) + expf(v1 - m);
#pragma unroll
  for (int off = 32; off; off >>= 1) s += __shfl_xor(s, off);
  float lse = m + logf(s);
  long o = (long)r * 128 + 2 * lane;
  if (fl){
    float2 w; w.x = v0 - lse; w.y = v1 - lse;
    *(float2*)&((float*)out)[o] = w;
  } else {
    *(unsigned int*)&((unsigned short*)out)[o] =
        (unsigned int)f2bf(v0 - lse) | ((unsigned int)f2bf(v1 - lse) << 16);
  }
}

extern "C" void kernel_launch(void* const* d_in, const int* in_sizes, int n_in,
                              void* d_out, int out_size, void* d_ws, size_t ws_size,
                              hipStream_t stream)
{
  const void* x    = d_in[0];
  const int*  erow = (const int*)d_in[1];
  const int*  ecol = (const int*)d_in[2];
  const void* eval = d_in[3];
  const void* Wres = d_in[4];
  const void* bres = d_in[5];
  const void* W1   = d_in[6];
  const void* b1   = d_in[7];
  const void* W2   = d_in[8];
  const void* b2   = d_in[9];
  const int N = in_sizes[0] / 256;   // 100000
  const int E = in_sizes[1];         // 1600000

  char* ws = (char*)d_ws;
  size_t szB = (size_t)N * 128 * 2;  // one bf16 [N,128] plane (25.6 MB)
  unsigned short* bufA  = (unsigned short*)ws;            // y1, then y2
  unsigned short* bufC  = (unsigned short*)(ws + szB);    // x1
  unsigned short* WresT = (unsigned short*)(ws + 2 * szB);
  unsigned short* W1T   = WresT + 256 * 128;
  unsigned short* W2T   = W1T   + 256 * 128;
  int*            flag  = (int*)(W2T + 256 * 128);
  int*            rs    = flag + 4;                        // [N+1] row_ptr
  unsigned short* zbuf  = (unsigned short*)d_out;          // z (bf16) in d_out

  prep_k<<<(E + 255) / 256, 256, 0, stream>>>(erow, rs, E, N,
                                              (const unsigned short*)x, flag);
  wtrans_all<<<320, 256, 0, stream>>>(Wres, W1, W2, WresT, W1T, W2T, flag);

  const int gBlocks = (N + 63) / 64;
  const int rBlocks = (N + 3) / 4;

  gemm_zy1<<<gBlocks, 256, 0, stream>>>(x, WresT, W1T, bres, zbuf, bufA, N, flag); // z + y1

  spmm1_f<<<rBlocks, 256, 0, stream>>>(rs, ecol, eval, bufA, zbuf, b1, bufC, N, flag); // x1

  gemm_y2<<<gBlocks, 256, 0, stream>>>(bufC, W2T, bufA, N);                            // y2

  spmm2_f<<<rBlocks, 256, 0, stream>>>(rs, ecol, eval, bufA, b2, d_out, N, flag);      // out
}